// Round 2
// baseline (196.576 us; speedup 1.0000x reference)
//
#include <hip/hip_runtime.h>

// CGLayer: MAX_L=2, B=2, N=256, TAU=16
// Key identity: sum_j over edge-level CG(rep, sph) commutes with the j-sum
// because rep is broadcast along j. So everything collapses to per-node work
// after computing S[l2][b,i,m2] = sum_j s_l2[b,i,j,m2].

#define N_NODES 256
#define TAU 16

__constant__ double g_FACT[8] = {1.0,1.0,2.0,6.0,24.0,120.0,720.0,5040.0};
__constant__ int g_TRI[15][3] = {
  {0,0,0},{0,1,1},{0,2,2},{1,0,1},{1,1,0},{1,1,1},{1,1,2},{1,2,1},{1,2,2},
  {2,0,2},{2,1,1},{2,1,2},{2,2,0},{2,2,1},{2,2,2}};
__constant__ int g_TRI_OFF[16] = {0,1,10,35,44,53,80,125,170,245,270,315,390,415,490,615};

// compile-time tables (indexed only with unrolled/constant indices in main kernel)
constexpr int OFF3[27] = {           // [l1*9 + l2*3 + l] -> offset into cg table, -1 invalid
  0,-1,-1,  -1,1,-1,   -1,-1,10,
  -1,35,-1, 44,53,80,  -1,125,170,
  -1,-1,245,-1,270,315,390,415,490};
constexpr int PAIRS[3][6][2] = {     // (l1,l2) block order per output l (matches reference concat order)
  {{0,0},{1,1},{2,2},{0,0},{0,0},{0,0}},
  {{0,1},{1,0},{1,1},{1,2},{2,1},{2,2}},
  {{0,2},{1,1},{1,2},{2,0},{2,1},{2,2}}};
constexpr int VOFF[3]   = {0,16,64};       // offsets into 144-float per-node vectors
constexpr int SOFF[3]   = {0,1,4};         // offsets into 9-float S vector
constexpr int OUT_OFF[3]= {0,8192,32768};  // flat output offsets per l

__device__ double cg_coef(int j1,int j2,int j3,int m1,int m2,int m3){
  double pre = sqrt((2.0*j3+1.0)*g_FACT[j3+j1-j2]*g_FACT[j3-j1+j2]*g_FACT[j1+j2-j3]/g_FACT[j1+j2+j3+1]);
  pre *= sqrt(g_FACT[j3+m3]*g_FACT[j3-m3]*g_FACT[j1-m1]*g_FACT[j1+m1]*g_FACT[j2-m2]*g_FACT[j2+m2]);
  int kmin = max(0, max(j2-j3-m1, j1-j3+m2));
  int kmax = min(j1+j2-j3, min(j1-m1, j2+m2));
  double s = 0.0;
  for (int k=kmin;k<=kmax;k++){
    double d = g_FACT[k]*g_FACT[j1+j2-j3-k]*g_FACT[j1-m1-k]*g_FACT[j2+m2-k]*g_FACT[j3-j2+m1+k]*g_FACT[j3-j1-m2+k];
    s += (k & 1) ? (-1.0/d) : (1.0/d);
  }
  return pre*s;
}

// builds the dense CG table (615 floats) in d_ws, matching the Python layout
__global__ void cg_init_kernel(float* __restrict__ tab){
  for (int s = threadIdx.x; s < 615; s += blockDim.x){
    int tr = 0;
    while (s >= g_TRI_OFF[tr+1]) tr++;
    int l1=g_TRI[tr][0], l2=g_TRI[tr][1], l=g_TRI[tr][2];
    int rem = s - g_TRI_OFF[tr];
    int d2 = 2*l2+1, dk = 2*l+1;
    int i1 = rem/(d2*dk); int r2 = rem%(d2*dk); int i2 = r2/dk; int ik = r2%dk;
    int m1=i1-l1, m2=i2-l2, m=ik-l;
    float val = 0.f;
    if (m1+m2 == m) val = (float)cg_coef(l1,l2,l,m1,m2,m);
    tab[s] = val;
  }
}

__global__ __launch_bounds__(256)
void cg_main(const float* __restrict__ v0, const float* __restrict__ v1, const float* __restrict__ v2,
             const float* __restrict__ s0, const float* __restrict__ s1, const float* __restrict__ s2,
             const float* __restrict__ wnl0, const float* __restrict__ wnl1, const float* __restrict__ wnl2,
             const float* __restrict__ wrel0, const float* __restrict__ wrel1, const float* __restrict__ wrel2,
             const int* __restrict__ conn, const float* __restrict__ cgtab,
             float* __restrict__ out, float* __restrict__ sums)
{
  __shared__ float sh_conn[256];
  __shared__ float sh_cg[615];
  __shared__ float sh_vmp[144];     // vmp[l][m][c]
  __shared__ float sh_S[9];         // S[l2][m2]
  __shared__ float sh_spart[112];
  __shared__ float sh_blk[6*5*256]; // nl CG blocks: [p][k][cd]
  __shared__ float sh_mnl[144];     // mixed_nl[l][k][t]
  __shared__ float sh_mix[256];     // split partials
  __shared__ float sh_rel[6*5*16];  // rel CG blocks: [p][k][c]
  __shared__ float sh_bsum;

  const int t  = threadIdx.x;
  const int bi = blockIdx.x;        // bi = b*256 + i
  const int b  = bi >> 8;

  // ---- stage conn row + cg table ----
  sh_conn[t] = (float)conn[(bi<<8) + t];
  for (int q=t; q<615; q+=256) sh_cg[q] = cgtab[q];
  __syncthreads();

  // ---- Phase A: vmp (threads 0..143) and S partials (threads 144..253) ----
  if (t < 144) {
    int l, m, c;
    if (t < 16)      { l=0; m=0;         c=t;    }
    else if (t < 64) { l=1; m=(t-16)>>4; c=t&15; }
    else             { l=2; m=(t-64)>>4; c=t&15; }
    const float* vl = (l==0) ? v0 : (l==1) ? v1 : v2;
    const int dm = 2*l+1;
    const float* base = vl + ((b*N_NODES)*dm + m)*TAU + c;
    const int stride = dm*TAU;
    float acc = 0.f;
    #pragma unroll 4
    for (int j=0;j<256;j++) acc += sh_conn[j] * base[j*stride];
    sh_vmp[t] = acc;
  } else {
    const int tt = t - 144;
    const float* sl = nullptr; int W=1, nth=32, bt=0;
    if (tt < 32)       { sl = s0; W=1; nth=32; bt=tt;    }
    else if (tt < 80)  { sl = s1; W=3; nth=48; bt=tt-32; }
    else if (tt < 110) { sl = s2; W=5; nth=30; bt=tt-80; }
    if (sl) {
      const int elems = 256*W;
      const float* p = sl + (size_t)bi*elems;
      float a=0.f;
      for (int e=bt; e<elems; e+=nth) a += p[e];
      sh_spart[tt] = a;
    }
  }
  __syncthreads();
  if (t < 9) {
    float a=0.f;
    if (t==0)       { for (int q=0; q<32; q++)     a += sh_spart[q]; }
    else if (t < 4) { for (int q=t-1; q<48; q+=3)  a += sh_spart[32+q]; }
    else            { for (int q=t-4; q<30; q+=5)  a += sh_spart[80+q]; }
    sh_S[t] = a;
  }
  __syncthreads();

  // ---- Phase B: node-level CG product + wnl mixing -> sh_mnl ----
  #pragma unroll
  for (int l=0; l<3; l++) {
    const int dk = 2*l+1;
    const int n_out = dk*TAU;
    const int nsplit = 256/n_out;               // 16,5,3
    const int cs = (256 + nsplit-1)/nsplit;     // 16,52,86
    const int o  = t % n_out;
    const int sp = t / n_out;
    const int k  = o >> 4, tc = o & 15;
    const float* wl = (l==0)?wnl0:(l==1)?wnl1:wnl2;
    const int np = (l==0)?3:6;

    __syncthreads();   // prior-l readers of sh_blk/sh_mix done
    // build all pair blocks: blk[p][kk][c*16+d]
    {
      const int c = t >> 4, d = t & 15;
      #pragma unroll
      for (int p=0; p<6; p++) {
        if (p >= np) break;
        const int l1 = PAIRS[l][p][0], l2 = PAIRS[l][p][1];
        const int d2 = 2*l2+1;
        const int coff = OFF3[l1*9+l2*3+l];
        #pragma unroll
        for (int kk=0; kk<dk; kk++) {
          const int m = kk - l;
          float a = 0.f;
          const int lo = (-l1 > m-l2) ? -l1 : m-l2;
          const int hi = ( l1 < m+l2) ?  l1 : m+l2;
          #pragma unroll
          for (int m1=lo; m1<=hi; m1++) {
            const int m2 = m - m1;
            const float C = sh_cg[coff + ((m1+l1)*d2 + (m2+l2))*dk + kk];
            a += C * sh_vmp[VOFF[l1] + (m1+l1)*TAU + c] * sh_vmp[VOFF[l2] + (m2+l2)*TAU + d];
          }
          sh_blk[(p*dk + kk)*256 + t] = a;
        }
      }
    }
    __syncthreads();
    // mixing: out[k,tc] = sum_p sum_cd blk[p][k][cd] * wnl[(p*256+cd)*16 + tc]
    float acc = 0.f;
    if (sp < nsplit) {
      const int lo = sp*cs, hi = (lo+cs < 256) ? lo+cs : 256;
      #pragma unroll
      for (int p=0; p<6; p++) {
        if (p >= np) break;
        const float* wrow = wl + (size_t)p*256*TAU + tc;
        const float* brow = &sh_blk[(p*dk + k)*256];
        float a = 0.f;
        #pragma unroll 4
        for (int cd=lo; cd<hi; cd++) a += brow[cd] * wrow[cd*TAU];
        acc += a;
      }
      sh_mix[sp*n_out + o] = acc;
    }
    __syncthreads();
    if (t < n_out) {
      float a = 0.f;
      for (int q=0; q<nsplit; q++) a += sh_mix[q*n_out + t];
      sh_mnl[VOFF[l] + t] = a;
    }
  }
  __syncthreads();

  // ---- Phase C: rel-level CG (with j-summed sph) + wrel mixing -> outputs ----
  #pragma unroll
  for (int l=0; l<3; l++) {
    const int dk = 2*l+1;
    const int n_out = dk*TAU;
    const int k = t >> 4, tc = t & 15;
    const float* wl = (l==0)?wrel0:(l==1)?wrel1:wrel2;
    const int np = (l==0)?3:6;

    __syncthreads();
    if (t < n_out) {
      #pragma unroll
      for (int p=0; p<6; p++) {
        if (p >= np) break;
        const int l1 = PAIRS[l][p][0], l2 = PAIRS[l][p][1];
        const int d2 = 2*l2+1;
        const int coff = OFF3[l1*9+l2*3+l];
        const int m = k - l;
        float a = 0.f;
        const int lo = (-l1 > m-l2) ? -l1 : m-l2;
        const int hi = ( l1 < m+l2) ?  l1 : m+l2;
        #pragma unroll
        for (int m1=lo; m1<=hi; m1++) {
          const int m2 = m - m1;
          const float C = sh_cg[coff + ((m1+l1)*d2 + (m2+l2))*dk + k];
          a += C * sh_mnl[VOFF[l1] + (m1+l1)*TAU + tc] * sh_S[SOFF[l2] + (m2+l2)];
        }
        sh_rel[(p*dk + k)*TAU + tc] = a;
      }
    }
    __syncthreads();
    float acc = 0.f;
    if (t < n_out) {
      #pragma unroll
      for (int p=0; p<6; p++) {
        if (p >= np) break;
        #pragma unroll
        for (int c=0; c<16; c++)
          acc += sh_rel[(p*dk + k)*TAU + c] * wl[(p*TAU + c)*TAU + tc];
      }
    }
    __syncthreads();
    if (t == 0) sh_bsum = 0.f;
    __syncthreads();
    if (t < n_out) {
      out[OUT_OFF[l] + ((size_t)bi*dk + k)*TAU + tc] = acc;
      atomicAdd(&sh_bsum, acc);
    }
    __syncthreads();
    if (t == 0) atomicAdd(&sums[l], sh_bsum);
  }
}

__global__ void normalize_kernel(float* __restrict__ out, const float* __restrict__ sums){
  int idx = blockIdx.x*blockDim.x + threadIdx.x;
  if (idx >= 73728) return;
  int l = (idx < 8192) ? 0 : (idx < 32768) ? 1 : 2;
  out[idx] = out[idx] / sums[l];
}

extern "C" void kernel_launch(void* const* d_in, const int* in_sizes, int n_in,
                              void* d_out, int out_size, void* d_ws, size_t ws_size,
                              hipStream_t stream) {
  // setup_inputs dict order: v0,s0,wnl0,wrel0, v1,s1,wnl1,wrel1, v2,s2,wnl2,wrel2, conn
  const float* v0    = (const float*)d_in[0];
  const float* s0    = (const float*)d_in[1];
  const float* wnl0  = (const float*)d_in[2];
  const float* wrel0 = (const float*)d_in[3];
  const float* v1    = (const float*)d_in[4];
  const float* s1    = (const float*)d_in[5];
  const float* wnl1  = (const float*)d_in[6];
  const float* wrel1 = (const float*)d_in[7];
  const float* v2    = (const float*)d_in[8];
  const float* s2    = (const float*)d_in[9];
  const float* wnl2  = (const float*)d_in[10];
  const float* wrel2 = (const float*)d_in[11];
  const int*   conn  = (const int*)d_in[12];
  float* out = (float*)d_out;

  float* cgtab = (float*)d_ws;        // 615 floats
  float* sums  = cgtab + 640;         // 3 floats, atomic accumulators

  hipMemsetAsync(sums, 0, 3*sizeof(float), stream);
  cg_init_kernel<<<1, 256, 0, stream>>>(cgtab);
  cg_main<<<512, 256, 0, stream>>>(v0, v1, v2, s0, s1, s2,
                                   wnl0, wnl1, wnl2, wrel0, wrel1, wrel2,
                                   conn, cgtab, out, sums);
  normalize_kernel<<<(73728+255)/256, 256, 0, stream>>>(out, sums);
}

// Round 3
// 136.177 us; speedup vs baseline: 1.4435x; 1.4435x over previous
//
#include <hip/hip_runtime.h>

// CGLayer: MAX_L=2, B=2, N=256, TAU=16
// Identity: sum_j of edge-level CG(rep, sph) commutes with the j-sum because
// rep is broadcast along j => everything collapses to per-node work after
// S[l2][b,i,m2] = sum_j s_l2[b,i,j,m2].
//
// Pipeline: k_prep (vmp + S + CG table + zero sums) -> k_main (per-node CG +
// mixing + out + per-l sums) -> k_norm. Kernel boundaries provide cross-XCD
// coherence for the ws handoffs.

#define N_NODES 256
#define TAU 16

// ws layout (floats)
#define CG_OFF   0        // 615
#define SUMS_OFF 640      // 3
#define VMP_OFF  1024     // 512*144
#define S_OFF    74752    // 512*16 (9 used)

__constant__ double g_FACT[8] = {1.0,1.0,2.0,6.0,24.0,120.0,720.0,5040.0};
__constant__ int g_TRI[15][3] = {
  {0,0,0},{0,1,1},{0,2,2},{1,0,1},{1,1,0},{1,1,1},{1,1,2},{1,2,1},{1,2,2},
  {2,0,2},{2,1,1},{2,1,2},{2,2,0},{2,2,1},{2,2,2}};
__constant__ int g_TRI_OFF[16] = {0,1,10,35,44,53,80,125,170,245,270,315,390,415,490,615};

constexpr int OFF3[27] = {           // [l1*9 + l2*3 + l] -> offset into cg table
  0,-1,-1,  -1,1,-1,   -1,-1,10,
  -1,35,-1, 44,53,80,  -1,125,170,
  -1,-1,245,-1,270,315,390,415,490};
constexpr int PAIRS[3][6][2] = {     // (l1,l2) order per output l (matches reference concat)
  {{0,0},{1,1},{2,2},{0,0},{0,0},{0,0}},
  {{0,1},{1,0},{1,1},{1,2},{2,1},{2,2}},
  {{0,2},{1,1},{1,2},{2,0},{2,1},{2,2}}};
constexpr int VOFF[3]   = {0,16,64};
constexpr int SOFF[3]   = {0,1,4};
constexpr int OUT_OFF[3]= {0,8192,32768};

__device__ double cg_coef(int j1,int j2,int j3,int m1,int m2,int m3){
  double pre = sqrt((2.0*j3+1.0)*g_FACT[j3+j1-j2]*g_FACT[j3-j1+j2]*g_FACT[j1+j2-j3]/g_FACT[j1+j2+j3+1]);
  pre *= sqrt(g_FACT[j3+m3]*g_FACT[j3-m3]*g_FACT[j1-m1]*g_FACT[j1+m1]*g_FACT[j2-m2]*g_FACT[j2+m2]);
  int kmin = max(0, max(j2-j3-m1, j1-j3+m2));
  int kmax = min(j1+j2-j3, min(j1-m1, j2+m2));
  double s = 0.0;
  for (int k=kmin;k<=kmax;k++){
    double d = g_FACT[k]*g_FACT[j1+j2-j3-k]*g_FACT[j1-m1-k]*g_FACT[j2+m2-k]*g_FACT[j3-j2+m1+k]*g_FACT[j3-j1-m2+k];
    s += (k & 1) ? (-1.0/d) : (1.0/d);
  }
  return pre*s;
}

// ---------------- K1: vmp + S sums + CG table + zero sums ----------------
__global__ __launch_bounds__(256)
void k_prep(const float* __restrict__ v0, const float* __restrict__ v1, const float* __restrict__ v2,
            const float* __restrict__ s0, const float* __restrict__ s1, const float* __restrict__ s2,
            const int* __restrict__ conn, float* __restrict__ ws)
{
  __shared__ float sh_conn[256];
  __shared__ float sh_red[4][9];
  const int t = threadIdx.x;
  const int blk = blockIdx.x;

  if (blk < 512) {
    // vmp[bi][f] = sum_j conn[bi,j] * v[b, j, f]
    const int bi = blk, b = bi >> 8;
    sh_conn[t] = (float)conn[(bi<<8) + t];
    __syncthreads();
    if (t < 144) {
      int l, m, c;
      if (t < 16)      { l=0; m=0;         c=t;    }
      else if (t < 64) { l=1; m=(t-16)>>4; c=t&15; }
      else             { l=2; m=(t-64)>>4; c=t&15; }
      const float* vl = (l==0) ? v0 : (l==1) ? v1 : v2;
      const int dm = 2*l+1;
      const float* base = vl + ((size_t)(b*N_NODES)*dm + m)*TAU + c;
      const int stride = dm*TAU;
      float a0=0.f,a1=0.f,a2=0.f,a3=0.f;
      for (int j=0;j<256;j+=4){
        a0 += sh_conn[j+0]*base[(j+0)*stride];
        a1 += sh_conn[j+1]*base[(j+1)*stride];
        a2 += sh_conn[j+2]*base[(j+2)*stride];
        a3 += sh_conn[j+3]*base[(j+3)*stride];
      }
      ws[VMP_OFF + bi*144 + t] = (a0+a1)+(a2+a3);
    } else if (blk == 0) {
      // CG table (float result, double eval) + zero sums
      for (int s = t-144; s < 615; s += 112) {
        int tr = 0;
        while (s >= g_TRI_OFF[tr+1]) tr++;
        int l1=g_TRI[tr][0], l2=g_TRI[tr][1], l=g_TRI[tr][2];
        int rem = s - g_TRI_OFF[tr];
        int d2 = 2*l2+1, dk = 2*l+1;
        int i1 = rem/(d2*dk); int r2 = rem%(d2*dk); int i2 = r2/dk; int ik = r2%dk;
        int m1=i1-l1, m2=i2-l2, m=ik-l;
        float val = 0.f;
        if (m1+m2 == m) val = (float)cg_coef(l1,l2,l,m1,m2,m);
        ws[CG_OFF + s] = val;
      }
      if (t == 144) { ws[SUMS_OFF]=0.f; ws[SUMS_OFF+1]=0.f; ws[SUMS_OFF+2]=0.f; }
    }
  } else {
    // S[bi][9]: per-m sums over j of s0/s1/s2 rows (coalesced)
    const int bi = blk - 512;
    const float* p0 = s0 + (size_t)bi*256;
    const float* p1 = s1 + (size_t)bi*768;
    const float* p2 = s2 + (size_t)bi*1280;
    float a[9];
    a[0] = p0[t];
    a[1] = p1[3*t+0]; a[2] = p1[3*t+1]; a[3] = p1[3*t+2];
    #pragma unroll
    for (int k=0;k<5;k++) a[4+k] = p2[5*t+k];
    #pragma unroll
    for (int m=0;m<9;m++){
      float x = a[m];
      #pragma unroll
      for (int off=32; off; off>>=1) x += __shfl_xor(x, off);
      a[m] = x;
    }
    const int wid = t>>6, lane = t&63;
    if (lane == 0) {
      #pragma unroll
      for (int m=0;m<9;m++) sh_red[wid][m] = a[m];
    }
    __syncthreads();
    if (t < 9) ws[S_OFF + bi*16 + t] = sh_red[0][t]+sh_red[1][t]+sh_red[2][t]+sh_red[3][t];
  }
}

// ---------------- K2: per-node CG products + mixing + sums ----------------
__global__ __launch_bounds__(512, 4)
void k_main(const float* __restrict__ wnl0, const float* __restrict__ wnl1, const float* __restrict__ wnl2,
            const float* __restrict__ wrel0, const float* __restrict__ wrel1, const float* __restrict__ wrel2,
            const float* __restrict__ ws, float* __restrict__ out, float* __restrict__ sums)
{
  __shared__ float sh_cg[615];
  __shared__ float sh_vmp[144];
  __shared__ float sh_S[9];
  __shared__ float sh_mnl[144];
  __shared__ float sh_blk[30*257];   // [pair*dk + kk][cd], stride 257 (bank-spread)
  __shared__ float sh_w[2][4096];    // double-buffered weight tile [256 cd][16 tc]
  __shared__ float sh_mix[512];
  __shared__ float sh_rel[480];
  __shared__ float sh_red[8];

  const int t  = threadIdx.x;
  const int bi = blockIdx.x;

  for (int q=t; q<615; q+=512) sh_cg[q] = ws[CG_OFF + q];
  if (t < 144)              sh_vmp[t]     = ws[VMP_OFF + bi*144 + t];
  if (t >= 160 && t < 169)  sh_S[t-160]   = ws[S_OFF + bi*16 + (t-160)];
  __syncthreads();

  // -------- Phase B: node-level CG + wnl mixing -> sh_mnl --------
  #pragma unroll
  for (int l=0; l<3; l++) {
    const int dk = 2*l+1;
    const int n_out = dk*TAU;
    const int np = (l==0)?3:6;
    const int nsplit = 512/n_out;               // 32,10,6
    const int cs = (256 + nsplit-1)/nsplit;     // 8,26,43
    const int o  = t % n_out;
    const int sp = t / n_out;
    const int k  = o >> 4, tc = o & 15;
    const float* wl = (l==0)?wnl0:(l==1)?wnl1:wnl2;

    // prefetch weight tile p=0 into registers (T14: issue early)
    const float* src0 = wl + (size_t)t*8;
    float4 ra = *(const float4*)(src0);
    float4 rb = *(const float4*)(src0+4);

    // build all pair blocks into sh_blk (two 256-thread halves, p literal)
    {
      const int c = (t>>4)&15, d = t&15;
      if (t < 256) {
        #pragma unroll
        for (int p=0; p<3; p++) {
          if (p < np) {
            const int l1 = PAIRS[l][p][0], l2 = PAIRS[l][p][1];
            const int d2 = 2*l2+1;
            const int coff = OFF3[l1*9+l2*3+l];
            #pragma unroll
            for (int kk=0; kk<dk; kk++) {
              const int m = kk - l;
              float a = 0.f;
              const int lo = (-l1 > m-l2) ? -l1 : m-l2;
              const int hi = ( l1 < m+l2) ?  l1 : m+l2;
              #pragma unroll
              for (int m1=lo; m1<=hi; m1++) {
                const int m2 = m - m1;
                const float C = sh_cg[coff + ((m1+l1)*d2 + (m2+l2))*dk + kk];
                a += C * sh_vmp[VOFF[l1] + (m1+l1)*TAU + c] * sh_vmp[VOFF[l2] + (m2+l2)*TAU + d];
              }
              sh_blk[(p*dk + kk)*257 + c*16 + d] = a;
            }
          }
        }
      } else {
        #pragma unroll
        for (int p=3; p<6; p++) {
          if (p < np) {
            const int l1 = PAIRS[l][p][0], l2 = PAIRS[l][p][1];
            const int d2 = 2*l2+1;
            const int coff = OFF3[l1*9+l2*3+l];
            #pragma unroll
            for (int kk=0; kk<dk; kk++) {
              const int m = kk - l;
              float a = 0.f;
              const int lo = (-l1 > m-l2) ? -l1 : m-l2;
              const int hi = ( l1 < m+l2) ?  l1 : m+l2;
              #pragma unroll
              for (int m1=lo; m1<=hi; m1++) {
                const int m2 = m - m1;
                const float C = sh_cg[coff + ((m1+l1)*d2 + (m2+l2))*dk + kk];
                a += C * sh_vmp[VOFF[l1] + (m1+l1)*TAU + c] * sh_vmp[VOFF[l2] + (m2+l2)*TAU + d];
              }
              sh_blk[(p*dk + kk)*257 + c*16 + d] = a;
            }
          }
        }
      }
    }
    __syncthreads();                 // blk visible; prior-l sh_w/sh_mix readers done
    { float4* wb = (float4*)&sh_w[0][t*8]; wb[0]=ra; wb[1]=rb; }
    __syncthreads();                 // w tile 0 visible

    float acc = 0.f;
    int buf = 0;
    for (int p=0; p<np; p++) {
      // prefetch next tile while mixing current (latency hides under FMAs)
      if (p+1 < np) {
        const float* srcn = wl + (size_t)(p+1)*4096 + (size_t)t*8;
        ra = *(const float4*)(srcn);
        rb = *(const float4*)(srcn+4);
      }
      if (sp < nsplit) {
        const int lo = sp*cs;
        const int hi = (lo+cs < 256) ? lo+cs : 256;
        const float* brow = &sh_blk[(p*dk + k)*257];
        const float* wrow = &sh_w[buf][tc];
        float aa = 0.f;
        #pragma unroll 4
        for (int cd=lo; cd<hi; cd++) aa += brow[cd] * wrow[cd*16];
        acc += aa;
      }
      if (p+1 < np) { float4* wb = (float4*)&sh_w[buf^1][t*8]; wb[0]=ra; wb[1]=rb; }
      __syncthreads();
      buf ^= 1;
    }
    if (sp < nsplit) sh_mix[sp*n_out + o] = acc;
    __syncthreads();
    if (t < n_out) {
      float a = 0.f;
      #pragma unroll
      for (int q=0; q<nsplit; q++) a += sh_mix[q*n_out + t];
      sh_mnl[VOFF[l] + t] = a;
    }
  }
  __syncthreads();

  // -------- Phase C: rel-level CG (j-summed sph) + wrel mixing --------
  #pragma unroll
  for (int l=0; l<3; l++) {
    const int dk = 2*l+1;
    const int n_out = dk*TAU;
    const int k = t >> 4, tc = t & 15;
    const float* wl = (l==0)?wrel0:(l==1)?wrel1:wrel2;
    const int np = (l==0)?3:6;

    __syncthreads();
    if (t < n_out) {
      #pragma unroll
      for (int p=0; p<6; p++) {
        if (p < np) {
          const int l1 = PAIRS[l][p][0], l2 = PAIRS[l][p][1];
          const int d2 = 2*l2+1;
          const int coff = OFF3[l1*9+l2*3+l];
          const int m = k - l;
          float a = 0.f;
          const int lo = (-l1 > m-l2) ? -l1 : m-l2;
          const int hi = ( l1 < m+l2) ?  l1 : m+l2;
          #pragma unroll
          for (int m1=lo; m1<=hi; m1++) {
            const int m2 = m - m1;
            const float C = sh_cg[coff + ((m1+l1)*d2 + (m2+l2))*dk + k];
            a += C * sh_mnl[VOFF[l1] + (m1+l1)*TAU + tc] * sh_S[SOFF[l2] + (m2+l2)];
          }
          sh_rel[(p*dk + k)*TAU + tc] = a;
        }
      }
    }
    __syncthreads();
    float acc = 0.f;
    if (t < n_out) {
      #pragma unroll
      for (int p=0; p<6; p++) {
        if (p < np) {
          #pragma unroll
          for (int c=0; c<16; c++)
            acc += sh_rel[(p*dk + k)*TAU + c] * wl[(p*TAU + c)*TAU + tc];
        }
      }
    }
    // block-wide sum of acc via shfl + one atomic
    float x = acc;
    #pragma unroll
    for (int off=32; off; off>>=1) x += __shfl_xor(x, off);
    const int wid = t>>6, lane = t&63;
    if (lane == 0) sh_red[wid] = x;
    __syncthreads();
    if (t == 0) {
      float s = 0.f;
      #pragma unroll
      for (int w=0; w<8; w++) s += sh_red[w];
      atomicAdd(&sums[l], s);
    }
    if (t < n_out) out[OUT_OFF[l] + ((size_t)bi*dk + k)*TAU + tc] = acc;
  }
}

// ---------------- K3: normalize ----------------
__global__ void k_norm(float* __restrict__ out, const float* __restrict__ sums){
  int idx = blockIdx.x*blockDim.x + threadIdx.x;
  if (idx >= 73728) return;
  int l = (idx < 8192) ? 0 : (idx < 32768) ? 1 : 2;
  out[idx] = out[idx] / sums[l];
}

extern "C" void kernel_launch(void* const* d_in, const int* in_sizes, int n_in,
                              void* d_out, int out_size, void* d_ws, size_t ws_size,
                              hipStream_t stream) {
  // setup_inputs order: v0,s0,wnl0,wrel0, v1,s1,wnl1,wrel1, v2,s2,wnl2,wrel2, conn
  const float* v0    = (const float*)d_in[0];
  const float* s0    = (const float*)d_in[1];
  const float* wnl0  = (const float*)d_in[2];
  const float* wrel0 = (const float*)d_in[3];
  const float* v1    = (const float*)d_in[4];
  const float* s1    = (const float*)d_in[5];
  const float* wnl1  = (const float*)d_in[6];
  const float* wrel1 = (const float*)d_in[7];
  const float* v2    = (const float*)d_in[8];
  const float* s2    = (const float*)d_in[9];
  const float* wnl2  = (const float*)d_in[10];
  const float* wrel2 = (const float*)d_in[11];
  const int*   conn  = (const int*)d_in[12];
  float* out = (float*)d_out;
  float* ws  = (float*)d_ws;
  float* sums = ws + SUMS_OFF;

  k_prep<<<1024, 256, 0, stream>>>(v0, v1, v2, s0, s1, s2, conn, ws);
  k_main<<<512, 512, 0, stream>>>(wnl0, wnl1, wnl2, wrel0, wrel1, wrel2, ws, out, sums);
  k_norm<<<288, 256, 0, stream>>>(out, sums);
}

// Round 4
// 134.356 us; speedup vs baseline: 1.4631x; 1.0136x over previous
//
#include <hip/hip_runtime.h>

// CGLayer: MAX_L=2, B=2, N=256, TAU=16
// Identity: sum_j of edge-level CG(rep, sph) commutes with the j-sum because
// rep is broadcast along j => per-node work after S[bi][m2] = sum_j s[bi][j][m2].
// k_prep (vmp + S + CG table + zero sums) -> k_main (CG products + mixing) -> k_norm.

#define TAU 16

// ws layout (floats)
#define CG_OFF   0        // 615
#define SUMS_OFF 640      // 3
#define VMP_OFF  1024     // 512*144
#define S_OFF    74752    // 512*16 (9 used)

__constant__ double g_FACT[8] = {1.0,1.0,2.0,6.0,24.0,120.0,720.0,5040.0};
__constant__ int g_TRI[15][3] = {
  {0,0,0},{0,1,1},{0,2,2},{1,0,1},{1,1,0},{1,1,1},{1,1,2},{1,2,1},{1,2,2},
  {2,0,2},{2,1,1},{2,1,2},{2,2,0},{2,2,1},{2,2,2}};
__constant__ int g_TRI_OFF[16] = {0,1,10,35,44,53,80,125,170,245,270,315,390,415,490,615};

constexpr int OFF3[27] = {           // [l1*9 + l2*3 + l] -> cg table offset
  0,-1,-1,  -1,1,-1,   -1,-1,10,
  -1,35,-1, 44,53,80,  -1,125,170,
  -1,-1,245,-1,270,315,390,415,490};
constexpr int PAIRS[3][6][2] = {     // (l1,l2) order per output l (reference concat order)
  {{0,0},{1,1},{2,2},{0,0},{0,0},{0,0}},
  {{0,1},{1,0},{1,1},{1,2},{2,1},{2,2}},
  {{0,2},{1,1},{1,2},{2,0},{2,1},{2,2}}};
constexpr int VOFF[3]   = {0,16,64};
constexpr int SOFF[3]   = {0,1,4};
constexpr int OUT_OFF[3]= {0,8192,32768};
constexpr int NPAIR[3]  = {3,6,6};
constexpr int FOFF[9]   = {0,16,32,48,64,80,96,112,128};  // vmp row -> feature offset

__device__ constexpr int RIDX(int l, int mi){ return l==0 ? 0 : (l==1 ? 1+mi : 4+mi); }

__device__ double cg_coef(int j1,int j2,int j3,int m1,int m2,int m3){
  double pre = sqrt((2.0*j3+1.0)*g_FACT[j3+j1-j2]*g_FACT[j3-j1+j2]*g_FACT[j1+j2-j3]/g_FACT[j1+j2+j3+1]);
  pre *= sqrt(g_FACT[j3+m3]*g_FACT[j3-m3]*g_FACT[j1-m1]*g_FACT[j1+m1]*g_FACT[j2-m2]*g_FACT[j2+m2]);
  int kmin = max(0, max(j2-j3-m1, j1-j3+m2));
  int kmax = min(j1+j2-j3, min(j1-m1, j2+m2));
  double s = 0.0;
  for (int k=kmin;k<=kmax;k++){
    double d = g_FACT[k]*g_FACT[j1+j2-j3-k]*g_FACT[j1-m1-k]*g_FACT[j2+m2-k]*g_FACT[j3-j2+m1+k]*g_FACT[j3-j1-m2+k];
    s += (k & 1) ? (-1.0/d) : (1.0/d);
  }
  return pre*s;
}

// one pair's blk rows: all indices compile-time after unroll (cg via scalar loads)
#define BUILD_P(L_, P_) do { \
  constexpr int l1_ = PAIRS[L_][P_][0], l2_ = PAIRS[L_][P_][1]; \
  constexpr int d2_ = 2*l2_+1, dkk_ = 2*(L_)+1; \
  constexpr int coff_ = OFF3[l1_*9+l2_*3+(L_)]; \
  _Pragma("unroll") \
  for (int kk=0; kk<dkk_; kk++) { \
    const int m_ = kk - (L_); \
    float a_ = 0.f; \
    _Pragma("unroll") \
    for (int m1=-l1_; m1<=l1_; m1++) { \
      const int m2 = m_ - m1; \
      if (m2 >= -l2_ && m2 <= l2_) \
        a_ += cgt[coff_ + ((m1+l1_)*d2_ + (m2+l2_))*dkk_ + kk] \
              * v_c[RIDX(l1_, m1+l1_)] * v_d[RIDX(l2_, m2+l2_)]; \
    } \
    sh_bm[((P_)*dkk_ + kk)*256 + (t&255)] = a_; \
  } \
} while(0)

// ---------------- K1: vmp (j-halved) + S sums + CG table + zero sums ----------------
__global__ __launch_bounds__(512)
void k_prep(const float* __restrict__ v0, const float* __restrict__ v1, const float* __restrict__ v2,
            const float* __restrict__ s0, const float* __restrict__ s1, const float* __restrict__ s2,
            const int* __restrict__ conn, float* __restrict__ ws)
{
  __shared__ float sh_conn[256];
  __shared__ float sh_v[2][144];
  __shared__ float sh_red[4][9];
  const int t = threadIdx.x;
  const int blk = blockIdx.x;

  if (blk < 512) {
    const int bi = blk, b = bi >> 8;
    if (t < 256) sh_conn[t] = (float)conn[((size_t)bi<<8) + t];
    __syncthreads();
    const int jh = t >> 8, tt = t & 255;
    if (tt < 144) {
      int l, m, c;
      if (tt < 16)      { l=0; m=0;          c=tt;    }
      else if (tt < 64) { l=1; m=(tt-16)>>4; c=tt&15; }
      else              { l=2; m=(tt-64)>>4; c=tt&15; }
      const float* vl = (l==0) ? v0 : (l==1) ? v1 : v2;
      const int dm = 2*l+1;
      const int stride = dm*TAU;
      const float* base = vl + (((size_t)b*256 + jh*128)*dm + m)*TAU + c;
      const float* cr = &sh_conn[jh*128];
      float a0=0.f,a1=0.f,a2=0.f,a3=0.f;
      for (int j=0;j<128;j+=4){
        a0 += cr[j+0]*base[(j+0)*stride];
        a1 += cr[j+1]*base[(j+1)*stride];
        a2 += cr[j+2]*base[(j+2)*stride];
        a3 += cr[j+3]*base[(j+3)*stride];
      }
      sh_v[jh][tt] = (a0+a1)+(a2+a3);
    }
    if (blk == 0 && t >= 144 && t < 256) {
      for (int s = t-144; s < 615; s += 112) {
        int tr = 0;
        while (s >= g_TRI_OFF[tr+1]) tr++;
        int l1=g_TRI[tr][0], l2=g_TRI[tr][1], l=g_TRI[tr][2];
        int rem = s - g_TRI_OFF[tr];
        int d2 = 2*l2+1, dk = 2*l+1;
        int i1 = rem/(d2*dk); int r2 = rem%(d2*dk); int i2 = r2/dk; int ik = r2%dk;
        int m1=i1-l1, m2=i2-l2, m=ik-l;
        float val = 0.f;
        if (m1+m2 == m) val = (float)cg_coef(l1,l2,l,m1,m2,m);
        ws[CG_OFF + s] = val;
      }
    }
    if (blk == 0 && t == 448) { ws[SUMS_OFF]=0.f; ws[SUMS_OFF+1]=0.f; ws[SUMS_OFF+2]=0.f; }
    __syncthreads();
    if (t < 144) ws[VMP_OFF + (size_t)bi*144 + t] = sh_v[0][t] + sh_v[1][t];
  } else {
    const int bi = blk - 512;
    if (t < 256) {
      const float* p0 = s0 + (size_t)bi*256;
      const float* p1 = s1 + (size_t)bi*768;
      const float* p2 = s2 + (size_t)bi*1280;
      float a[9];
      a[0] = p0[t];
      a[1] = p1[3*t+0]; a[2] = p1[3*t+1]; a[3] = p1[3*t+2];
      #pragma unroll
      for (int k=0;k<5;k++) a[4+k] = p2[5*t+k];
      #pragma unroll
      for (int m=0;m<9;m++){
        float x = a[m];
        #pragma unroll
        for (int off=32; off; off>>=1) x += __shfl_xor(x, off);
        a[m] = x;
      }
      const int wid = t>>6, lane = t&63;
      if (lane == 0) {
        #pragma unroll
        for (int m=0;m<9;m++) sh_red[wid][m] = a[m];
      }
    }
    __syncthreads();
    if (t < 9) ws[S_OFF + (size_t)bi*16 + t] = sh_red[0][t]+sh_red[1][t]+sh_red[2][t]+sh_red[3][t];
  }
}

// ---------------- K2: per-node CG products + mixing + sums ----------------
__global__ __launch_bounds__(512, 4)
void k_main(const float* __restrict__ wnl0, const float* __restrict__ wnl1, const float* __restrict__ wnl2,
            const float* __restrict__ wrel0, const float* __restrict__ wrel1, const float* __restrict__ wrel2,
            const float* __restrict__ ws, float* __restrict__ out, float* __restrict__ sums)
{
  __shared__ __align__(16) float sh_bm[7680];    // blk [30][256]  /  mix [80][68] overlay
  __shared__ __align__(16) float sh_wt[2][4096]; // transposed w tile [tc][cd], double-buffered
  __shared__ float sh_mnl[144];
  __shared__ float sh_S[9];
  __shared__ float sh_rel[480];
  __shared__ float sh_red[8];

  const int t  = threadIdx.x;
  const int bi = blockIdx.x;
  const float* __restrict__ cgt = ws + CG_OFF;

  // per-thread vmp fragments (build uses only registers; zero LDS reads in build)
  const int bc = (t>>4)&15, bd = t&15;
  float v_c[9], v_d[9];
  {
    const float* vb = ws + VMP_OFF + (size_t)bi*144;
    #pragma unroll
    for (int r=0;r<9;r++){ v_c[r] = vb[FOFF[r]+bc]; v_d[r] = vb[FOFF[r]+bd]; }
  }
  if (t < 9) sh_S[t] = ws[S_OFF + (size_t)bi*16 + t];

  const int tg = t>>6, ksub = t&63;   // wave id = tc-pair group; lane = K-chunk
  const int tc0 = tg*2;
  const int tcw = (t&1)*8, cdw = t>>1; // w-transpose staging coords

  // -------- Phase B: node-level CG + wnl mixing -> sh_mnl --------
  #pragma unroll
  for (int l=0; l<3; l++) {
    const int dk = 2*l+1;
    const int n_out = dk*16;
    const int np = NPAIR[l];
    const float* wl = (l==0)?wnl0:(l==1)?wnl1:wnl2;

    // prefetch w tile p=0 (issue early; hidden under build VALU)
    float4 ra = *(const float4*)(wl + (size_t)t*8);
    float4 rb = *(const float4*)(wl + (size_t)t*8 + 4);

    // build pair blocks (half 0: p<3, half 1: p>=3), constant-indexed
    if (l == 0) {
      if (t < 256) { BUILD_P(0,0); BUILD_P(0,1); BUILD_P(0,2); }
    } else if (l == 1) {
      if (t < 256) { BUILD_P(1,0); BUILD_P(1,1); BUILD_P(1,2); }
      else         { BUILD_P(1,3); BUILD_P(1,4); BUILD_P(1,5); }
    } else {
      if (t < 256) { BUILD_P(2,0); BUILD_P(2,1); BUILD_P(2,2); }
      else         { BUILD_P(2,3); BUILD_P(2,4); BUILD_P(2,5); }
    }

    float acc[5][2];
    #pragma unroll
    for (int k=0;k<5;k++){ acc[k][0]=0.f; acc[k][1]=0.f; }

    __syncthreads();            // build done; prior-l sh_bm/sh_wt readers done
    {
      float* wt0 = sh_wt[0];
      #pragma unroll
      for (int i=0;i<4;i++) wt0[(tcw+i)*256 + cdw]   = ((const float*)&ra)[i];
      #pragma unroll
      for (int i=0;i<4;i++) wt0[(tcw+4+i)*256 + cdw] = ((const float*)&rb)[i];
    }
    __syncthreads();            // w tile 0 visible

    int buf = 0;
    for (int p=0; p<np; p++) {
      if (p+1 < np) {           // prefetch next tile under the FMAs
        ra = *(const float4*)(wl + (size_t)(p+1)*4096 + (size_t)t*8);
        rb = *(const float4*)(wl + (size_t)(p+1)*4096 + (size_t)t*8 + 4);
      }
      const float* wt = sh_wt[buf];
      const float4 w0 = *(const float4*)&wt[(tc0  )*256 + ksub*4];
      const float4 w1 = *(const float4*)&wt[(tc0+1)*256 + ksub*4];
      #pragma unroll
      for (int k=0;k<5;k++) if (k < dk) {
        const float4 bk = *(const float4*)&sh_bm[(p*dk+k)*256 + ksub*4];
        acc[k][0] += bk.x*w0.x + bk.y*w0.y + bk.z*w0.z + bk.w*w0.w;
        acc[k][1] += bk.x*w1.x + bk.y*w1.y + bk.z*w1.z + bk.w*w1.w;
      }
      if (p+1 < np) {
        float* wtn = sh_wt[buf^1];
        #pragma unroll
        for (int i=0;i<4;i++) wtn[(tcw+i)*256 + cdw]   = ((const float*)&ra)[i];
        #pragma unroll
        for (int i=0;i<4;i++) wtn[(tcw+4+i)*256 + cdw] = ((const float*)&rb)[i];
      }
      __syncthreads();
      buf ^= 1;
    }

    // K-chunk reduction via LDS scratch overlaid on dead blk region
    #pragma unroll
    for (int k=0;k<5;k++) if (k < dk) {
      sh_bm[(k*16 + tc0  )*68 + ksub] = acc[k][0];
      sh_bm[(k*16 + tc0+1)*68 + ksub] = acc[k][1];
    }
    __syncthreads();
    if (t < n_out) {
      const float* row = &sh_bm[t*68];
      float r0=0.f,r1=0.f,r2=0.f,r3=0.f;
      #pragma unroll
      for (int q=0;q<16;q++){
        const float4 v = *(const float4*)&row[q*4];
        r0+=v.x; r1+=v.y; r2+=v.z; r3+=v.w;
      }
      sh_mnl[VOFF[l]+t] = (r0+r1)+(r2+r3);
    }
    __syncthreads();
  }

  // -------- Phase C: rel-level CG (j-summed sph) + wrel mixing --------
  #pragma unroll
  for (int l=0; l<3; l++) {
    const int dk = 2*l+1;
    const int n_out = dk*16;
    const int k = t >> 4, tc = t & 15;
    const float* wl = (l==0)?wrel0:(l==1)?wrel1:wrel2;
    const int np = NPAIR[l];

    __syncthreads();
    if (t < n_out) {
      #pragma unroll
      for (int p=0; p<6; p++) {
        if (p < np) {
          const int l1 = PAIRS[l][p][0], l2 = PAIRS[l][p][1];
          const int d2 = 2*l2+1;
          const int coff = OFF3[l1*9+l2*3+l];
          const int m = k - l;
          float a = 0.f;
          const int lo = (-l1 > m-l2) ? -l1 : m-l2;
          const int hi = ( l1 < m+l2) ?  l1 : m+l2;
          #pragma unroll
          for (int m1=-2; m1<=2; m1++) {
            if (m1 >= lo && m1 <= hi) {
              const int m2 = m - m1;
              const float C = cgt[coff + ((m1+l1)*d2 + (m2+l2))*dk + k];
              a += C * sh_mnl[VOFF[l1] + (m1+l1)*TAU + tc] * sh_S[SOFF[l2] + (m2+l2)];
            }
          }
          sh_rel[(p*dk + k)*TAU + tc] = a;
        }
      }
    }
    __syncthreads();
    float acc = 0.f;
    if (t < n_out) {
      #pragma unroll
      for (int p=0; p<6; p++) {
        if (p < np) {
          #pragma unroll
          for (int c=0; c<16; c++)
            acc += sh_rel[(p*dk + k)*TAU + c] * wl[(p*TAU + c)*TAU + tc];
        }
      }
    }
    float x = acc;
    #pragma unroll
    for (int off=32; off; off>>=1) x += __shfl_xor(x, off);
    const int lane = t & 63;
    if (lane == 0) sh_red[t>>6] = x;
    __syncthreads();
    if (t == 0) {
      float s = 0.f;
      #pragma unroll
      for (int w=0; w<8; w++) s += sh_red[w];
      atomicAdd(&sums[l], s);
    }
    if (t < n_out) out[OUT_OFF[l] + ((size_t)bi*dk + k)*TAU + tc] = acc;
  }
}

// ---------------- K3: normalize ----------------
__global__ void k_norm(float* __restrict__ out, const float* __restrict__ sums){
  int idx = blockIdx.x*blockDim.x + threadIdx.x;
  if (idx >= 73728) return;
  int l = (idx < 8192) ? 0 : (idx < 32768) ? 1 : 2;
  out[idx] = out[idx] / sums[l];
}

extern "C" void kernel_launch(void* const* d_in, const int* in_sizes, int n_in,
                              void* d_out, int out_size, void* d_ws, size_t ws_size,
                              hipStream_t stream) {
  // setup_inputs order: v0,s0,wnl0,wrel0, v1,s1,wnl1,wrel1, v2,s2,wnl2,wrel2, conn
  const float* v0    = (const float*)d_in[0];
  const float* s0    = (const float*)d_in[1];
  const float* wnl0  = (const float*)d_in[2];
  const float* wrel0 = (const float*)d_in[3];
  const float* v1    = (const float*)d_in[4];
  const float* s1    = (const float*)d_in[5];
  const float* wnl1  = (const float*)d_in[6];
  const float* wrel1 = (const float*)d_in[7];
  const float* v2    = (const float*)d_in[8];
  const float* s2    = (const float*)d_in[9];
  const float* wnl2  = (const float*)d_in[10];
  const float* wrel2 = (const float*)d_in[11];
  const int*   conn  = (const int*)d_in[12];
  float* out = (float*)d_out;
  float* ws  = (float*)d_ws;
  float* sums = ws + SUMS_OFF;

  k_prep<<<1024, 512, 0, stream>>>(v0, v1, v2, s0, s1, s2, conn, ws);
  k_main<<<512, 512, 0, stream>>>(wnl0, wnl1, wnl2, wrel0, wrel1, wrel2, ws, out, sums);
  k_norm<<<288, 256, 0, stream>>>(out, sums);
}